// Round 13
// baseline (4965.105 us; speedup 1.0000x reference)
//
#include <hip/hip_runtime.h>

typedef float f32x4 __attribute__((ext_vector_type(4)));
typedef short short8 __attribute__((ext_vector_type(8)));

#define NWG_S 16   // serial-chain worker workgroups
#define AR 32      // a-rows per WG (512/16)
#define OR 25      // output rows per WG (400/16)

__device__ __forceinline__ unsigned short f2bf(float f) {
  unsigned int u = __float_as_uint(f);
  u += 0x7fffu + ((u >> 16) & 1u);
  return (unsigned short)(u >> 16);
}

// ---------------- workspace layout (bytes) ----------------
// 0       : w2t       bf16[128][576]  transposed conv2 weights (147456)
// 147456  : feats_sum f32 [128][128]  (65536)   zeroed each launch
// 212992  : ev        f32 [896]       (3584)
// 216576  : base      f32 [128][400]  (204800)
// 421376  : pe        f32 [2][16][400] partial logits, ping-pong (51200)
// 472576  : seq       int [16]        per-WG step flags, zeroed each launch

// ================= prep: zero accumulators, transpose conv2_w, fce branch ==
__global__ __launch_bounds__(256) void prep_k(
    const float* __restrict__ enc, const float* __restrict__ fce_w,
    const float* __restrict__ fce_b, const float* __restrict__ conv2_w,
    unsigned short* __restrict__ w2t, float* __restrict__ ev,
    float* __restrict__ feats_sum, int* __restrict__ seq) {
  int b = blockIdx.x, t = threadIdx.x;
  if (b < 48) {
    for (int i = b * 256 + t; i < 16400; i += 48 * 256) {
      if (i < 16384) feats_sum[i] = 0.f;
      else seq[i - 16384] = 0;
    }
    for (int i = b * 256 + t; i < 73728; i += 48 * 256) {
      int oc = i / 576, k = i - oc * 576;
      int p = k >> 6, ic = k & 63;
      int ky = p / 3, kx = p - ky * 3;
      w2t[i] = f2bf(conv2_w[((oc * 64 + ic) * 3 + ky) * 3 + kx]);
    }
  } else {
    // ev[n*64+o] = relu(enc[n,:] . fce_w[o,:] + fce_b[o]); 16 blocks x 56 outs
    if (t < 224) {
      int o_l = t >> 2, part = t & 3;
      int o_glob = (b - 48) * 56 + o_l;
      int n = o_glob >> 6, o = o_glob & 63;
      const f32x4* e4 = (const f32x4*)(enc + n * 2048);
      const f32x4* w4 = (const f32x4*)(fce_w + o * 2048);
      float s = 0.f;
      for (int d = part * 128; d < part * 128 + 128; ++d) {
        f32x4 a = e4[d], w = w4[d];
        s += a.x * w.x + a.y * w.y + a.z * w.z + a.w * w.w;
      }
      s += __shfl_xor(s, 1);
      s += __shfl_xor(s, 2);
      if (part == 0) ev[o_glob] = fmaxf(s + fce_b[o], 0.f);
    }
  }
}

// ================ fused CNN: conv1 -> rolling LDS window -> conv2 MFMA =====
// Block = (frame, 16-row strip). Per conv2 row oy: stage conv1 rows 2oy,2oy+1
// into a 4-slot rolling window (each px computed ONCE), then 18 K-steps of
// 16x16x32 MFMA per wave consuming rows 2oy-1..2oy+1. B-frags come straight
// from w2t (global, L2-hot). No c1 buffer exists anywhere.
// LDS layout: tile[slot][cst][ch^((cst&7)<<3)] — XOR swizzle keeps the
// stride-2 A-reads ~conflict-free at pitch 64.
__global__ __launch_bounds__(1024) void cnn_k(
    const float* __restrict__ vid, const float* __restrict__ c1w,
    const float* __restrict__ c1b, const unsigned short* __restrict__ w2t,
    const float* __restrict__ c2b, float* __restrict__ feats_sum) {
  __shared__ unsigned short tile[4][130 * 64];  // 66.6 KB
  __shared__ float fred[128];
  int t = threadIdx.x;
  int f = blockIdx.x >> 2, hs = blockIdx.x & 3;
  const int oy0 = hs * 16;

  // MFMA-phase geometry: 16 waves = 4 m-tiles x 4 n-groups(2 oc-tiles each)
  int wave = t >> 6, lane = t & 63;
  int mt = wave & 3, ng = wave >> 2;
  int or_ = lane & 15, kq8 = (lane >> 4) * 8;
  int ox = mt * 16 + or_;
  int oc0 = (2 * ng) * 16 + or_, oc1 = (2 * ng + 1) * 16 + or_;
  float bias0 = c2b[oc0], bias1 = c2b[oc1];
  const unsigned short* bp0 = w2t + oc0 * 576 + kq8;
  const unsigned short* bp1 = w2t + oc1 * 576 + kq8;
  f32x4 rsum0 = {0.f, 0.f, 0.f, 0.f}, rsum1 = {0.f, 0.f, 0.f, 0.f};

  if (t < 128) fred[t] = 0.f;
  if (t < 32) {  // zero column 0 (ix = -1 halo) of all 4 slots
    *(uint4*)&tile[t >> 3][(t & 7) * 8] = make_uint4(0u, 0u, 0u, 0u);
  }
  {  // ---- prologue: stage conv1 row 2*oy0-1 (8 threads/px, 8 oc each) ----
    int iy = 2 * oy0 - 1;
    int col = t >> 3, sub = t & 7;
    int cst = col + 1, X = (cst & 7) << 3;
    unsigned short pk[8];
    if (iy >= 0) {
      float inv[27];
#pragma unroll
      for (int c = 0; c < 3; ++c)
#pragma unroll
        for (int ky1 = 0; ky1 < 3; ++ky1) {
          int vy = 2 * iy - 1 + ky1;
#pragma unroll
          for (int kx1 = 0; kx1 < 3; ++kx1) {
            int vx = 2 * col - 1 + kx1;
            bool ok = (vy >= 0 && vy < 256 && vx >= 0 && vx < 256);
            inv[c * 9 + ky1 * 3 + kx1] =
                ok ? vid[((f * 3 + c) * 256 + vy) * 256 + vx] : 0.f;
          }
        }
#pragma unroll
      for (int j = 0; j < 8; ++j) {
        int oc = sub * 8 + j;
        float s = c1b[oc];
#pragma unroll
        for (int i = 0; i < 27; ++i) s += c1w[oc * 27 + i] * inv[i];
        pk[j] = f2bf(fmaxf(s, 0.f));
      }
    } else {
#pragma unroll
      for (int j = 0; j < 8; ++j) pk[j] = 0;
    }
    *(uint4*)&tile[iy & 3][cst * 64 + ((sub * 8) ^ X)] = *(const uint4*)pk;
  }
  __syncthreads();

  for (int oy = oy0; oy < oy0 + 16; ++oy) {
    {  // ---- stage conv1 rows 2oy, 2oy+1 (4 threads/px, 16 oc each) ----
      int px = t >> 2, sub = t & 3;
      int rs = px >> 7, col = px & 127;
      int iy = 2 * oy + rs;
      int cst = col + 1, X = (cst & 7) << 3;
      float inv[27];
#pragma unroll
      for (int c = 0; c < 3; ++c)
#pragma unroll
        for (int ky1 = 0; ky1 < 3; ++ky1) {
          int vy = 2 * iy - 1 + ky1;
#pragma unroll
          for (int kx1 = 0; kx1 < 3; ++kx1) {
            int vx = 2 * col - 1 + kx1;
            bool ok = (vy >= 0 && vy < 256 && vx >= 0 && vx < 256);
            inv[c * 9 + ky1 * 3 + kx1] =
                ok ? vid[((f * 3 + c) * 256 + vy) * 256 + vx] : 0.f;
          }
        }
      unsigned short* dst = &tile[iy & 3][cst * 64];
#pragma unroll
      for (int gg = 0; gg < 2; ++gg) {
        unsigned short pk[8];
#pragma unroll
        for (int j = 0; j < 8; ++j) {
          int oc = sub * 16 + gg * 8 + j;
          float s = c1b[oc];
#pragma unroll
          for (int i = 0; i < 27; ++i) s += c1w[oc * 27 + i] * inv[i];
          pk[j] = f2bf(fmaxf(s, 0.f));
        }
        *(uint4*)&dst[(sub * 16 + gg * 8) ^ X] = *(const uint4*)pk;
      }
    }
    __syncthreads();

    // ---- conv2 row oy: 18 K-steps x 2 MFMA ----
    f32x4 acc0 = {0.f, 0.f, 0.f, 0.f}, acc1 = {0.f, 0.f, 0.f, 0.f};
#pragma unroll
    for (int kk = 0; kk < 18; ++kk) {
      int p = kk >> 1, ic0 = (kk & 1) * 32;
      int ky = p / 3, kx = p - ky * 3;
      int iyr = 2 * oy - 1 + ky;
      int cst = 2 * ox + kx;
      short8 av = *(const short8*)&tile[iyr & 3]
                      [cst * 64 + ((ic0 + kq8) ^ ((cst & 7) << 3))];
      short8 bv0 = *(const short8*)&bp0[p * 64 + ic0];
      short8 bv1 = *(const short8*)&bp1[p * 64 + ic0];
      acc0 = __builtin_amdgcn_mfma_f32_16x16x32_bf16(av, bv0, acc0, 0, 0, 0);
      acc1 = __builtin_amdgcn_mfma_f32_16x16x32_bf16(av, bv1, acc1, 0, 0, 0);
    }
#pragma unroll
    for (int q = 0; q < 4; ++q) {
      rsum0[q] += fmaxf(acc0[q] + bias0, 0.f);
      rsum1[q] += fmaxf(acc1[q] + bias1, 0.f);
    }
    __syncthreads();  // readers done before next stage overwrites slots
  }

  // ---- epilogue: reduce px dims, one atomic per (wave, oc) ----
  float s0 = rsum0[0] + rsum0[1] + rsum0[2] + rsum0[3];
  float s1 = rsum1[0] + rsum1[1] + rsum1[2] + rsum1[3];
  s0 += __shfl_xor(s0, 16);
  s0 += __shfl_xor(s0, 32);
  s1 += __shfl_xor(s1, 16);
  s1 += __shfl_xor(s1, 32);
  if (lane < 16) {
    atomicAdd(&fred[oc0], s0);
    atomicAdd(&fred[oc1], s1);
  }
  __syncthreads();
  if (t < 128) atomicAdd(&feats_sum[f * 128 + t], fred[t]);
}

// ====== base[t][c] = feats_t.Wf + ev.We + fc_b (time-independent part) =====
__global__ __launch_bounds__(256) void base_k(
    const float* __restrict__ feats_sum, const float* __restrict__ ev,
    const float* __restrict__ fc_w, const float* __restrict__ fc_b,
    float* __restrict__ base) {
  __shared__ float xv[1024];
  int tfr = blockIdx.x, t = threadIdx.x;
  for (int i = t; i < 1024; i += 256)
    xv[i] = (i < 128) ? feats_sum[tfr * 128 + i] * (1.f / 4096.f) : ev[i - 128];
  __syncthreads();
  for (int c = t; c < 400; c += 256) {
    const float* wr = fc_w + c * 1536;
    float s = fc_b[c];
    for (int k = 0; k < 1024; k += 4) {
      f32x4 w4 = *(const f32x4*)&wr[k];
      s += w4.x * xv[k] + w4.y * xv[k + 1] + w4.z * xv[k + 2] + w4.w * xv[k + 3];
    }
    base[tfr * 400 + c] = s;
  }
}

// ============ serial chain: 128 steps, ONE partial-logit exchange per step =
// (R4 known-good version, measured ~530 us.)
__global__ __launch_bounds__(256) void serial_k(
    const float* __restrict__ fca_w, const float* __restrict__ fca_b,
    const float* __restrict__ fc_w, const float* __restrict__ action,
    const float* __restrict__ base, float* __restrict__ pe,
    int* __restrict__ seq, float* __restrict__ out) {
  int g = blockIdx.x;   // 0..15
  int t = threadIdx.x;
  __shared__ float wa[AR * 400];    // fca_w rows [g*32,+32)             51.2 KB
  __shared__ float wb2[400 * 33];   // fc_w[:,1024+g*32 ..+32] pad 33    52.8 KB
  __shared__ float sh_p[400];       // current softmax vector (local copy)
  __shared__ float sh_a[AR];        // own a slice
  __shared__ float sred[4];

  // ---- one-time LDS weight staging ----
  for (int i = t; i < AR * 400; i += 256) wa[i] = fca_w[g * AR * 400 + i];
  for (int i = t; i < 400 * 32; i += 256) {
    int r = i >> 5, c = i & 31;
    wb2[r * 33 + c] = fc_w[r * 1536 + 1024 + g * AR + c];
  }
  for (int i = t; i < 400; i += 256) sh_p[i] = action[i];  // step-0 input (raw)
  float fab = fca_b[g * AR + (t >> 3)];
  const int row = t >> 3;       // 0..31
  const int p4 = (t & 7) * 4;
  const unsigned lo = g * OR;
  __syncthreads();

  for (int step = 0; step < 128; ++step) {
    {  // ---- phase A: sh_a[row] = relu(wa[row,:].sh_p + b) ----
      const float* wrow = &wa[row * 400];
      float s = 0.f;
#pragma unroll
      for (int k = 0; k < 12; ++k) {
        f32x4 w = *(const f32x4*)&wrow[p4 + 32 * k];
        f32x4 x = *(const f32x4*)&sh_p[p4 + 32 * k];
        s += w.x * x.x + w.y * x.y + w.z * x.z + w.w * x.w;
      }
      if ((t & 7) < 4) {  // tail cols 384..399
        f32x4 w = *(const f32x4*)&wrow[384 + p4];
        f32x4 x = *(const f32x4*)&sh_p[384 + p4];
        s += w.x * x.x + w.y * x.y + w.z * x.z + w.w * x.w;
      }
      s += __shfl_xor(s, 1);
      s += __shfl_xor(s, 2);
      s += __shfl_xor(s, 4);
      if ((t & 7) == 0) sh_a[row] = fmaxf(s + fab, 0.f);
    }
    // prefetch base row (immutable, cached; hidden under phase A)
    float breg0 = base[step * 400 + t];
    float breg1 = (t < 144) ? base[step * 400 + 256 + t] : 0.f;
    __syncthreads();

    // ---- partial logits published write-through (sc0/sc1, no L2 dirty) ----
    float* peb = pe + ((step & 1) * 16 + g) * 400;
    for (int c = t; c < 400; c += 256) {
      float s = 0.f;
#pragma unroll
      for (int j = 0; j < 32; ++j) s += wb2[c * 33 + j] * sh_a[j];
      __hip_atomic_store(&peb[c], s, __ATOMIC_RELAXED, __HIP_MEMORY_SCOPE_AGENT);
    }
    asm volatile("s_waitcnt vmcnt(0)" ::: "memory");  // per-wave drain to coherence point
    __syncthreads();                                   // all waves drained
    if (t == 0)
      __hip_atomic_store(&seq[g], step + 1, __ATOMIC_RELAXED, __HIP_MEMORY_SCOPE_AGENT);

    // ---- wait for all 16 partials ----
    if (t < 16) {
      while (__hip_atomic_load(&seq[t], __ATOMIC_RELAXED, __HIP_MEMORY_SCOPE_AGENT) <
             step + 1)
        __builtin_amdgcn_s_sleep(1);
    }
    __syncthreads();
    __builtin_amdgcn_fence(__ATOMIC_ACQUIRE, "agent");  // flash-inv (no writeback)

    // ---- combine: logits = base + sum_h pe_h; softmax fully local ----
    const float* pebase = pe + (step & 1) * (16 * 400);
    float l0 = breg0, l1 = breg1;
#pragma unroll
    for (int h = 0; h < 16; ++h) l0 += pebase[h * 400 + t];
    float e0 = __expf(l0), e1 = 0.f;
    if (t < 144) {
#pragma unroll
      for (int h = 0; h < 16; ++h) l1 += pebase[h * 400 + 256 + t];
      e1 = __expf(l1);
    }
    float sp = e0 + e1;
    sp += __shfl_xor(sp, 1);
    sp += __shfl_xor(sp, 2);
    sp += __shfl_xor(sp, 4);
    sp += __shfl_xor(sp, 8);
    sp += __shfl_xor(sp, 16);
    sp += __shfl_xor(sp, 32);
    if ((t & 63) == 0) sred[t >> 6] = sp;
    __syncthreads();
    float S = sred[0] + sred[1] + sred[2] + sred[3];
    float q0 = e0 / S;
    sh_p[t] = q0;
    if ((unsigned)(t - lo) < (unsigned)OR) out[step * 400 + t] = q0;
    if (t < 144) {
      float q1 = e1 / S;
      sh_p[256 + t] = q1;
      if ((unsigned)(256 + t - lo) < (unsigned)OR) out[step * 400 + 256 + t] = q1;
    }
    __syncthreads();  // sh_p ready for next phase A (and sh_a reusable)
  }
}

extern "C" void kernel_launch(void* const* d_in, const int* in_sizes, int n_in,
                              void* d_out, int out_size, void* d_ws, size_t ws_size,
                              hipStream_t stream) {
  (void)in_sizes; (void)n_in; (void)out_size; (void)ws_size;
  const float* enc    = (const float*)d_in[0];
  const float* vid    = (const float*)d_in[1];
  const float* action = (const float*)d_in[2];
  const float* c1w    = (const float*)d_in[3];
  const float* c1b    = (const float*)d_in[4];
  const float* c2w    = (const float*)d_in[5];
  const float* c2b    = (const float*)d_in[6];
  const float* fce_w  = (const float*)d_in[7];
  const float* fce_b  = (const float*)d_in[8];
  const float* fca_w  = (const float*)d_in[9];
  const float* fca_b  = (const float*)d_in[10];
  const float* fc_w   = (const float*)d_in[11];
  const float* fc_b   = (const float*)d_in[12];
  // d_in[13..16] (wih/whh/bih/bhh): dead code — LSTM state never reaches the output.
  float* out = (float*)d_out;
  char* ws = (char*)d_ws;
  unsigned short* w2t = (unsigned short*)(ws + 0);
  float* feats_sum    = (float*)(ws + 147456);
  float* ev           = (float*)(ws + 212992);
  float* base         = (float*)(ws + 216576);
  float* pe           = (float*)(ws + 421376);
  int*   seq          = (int*)(ws + 472576);

  hipLaunchKernelGGL(prep_k, dim3(64), dim3(256), 0, stream,
                     enc, fce_w, fce_b, c2w, w2t, ev, feats_sum, seq);
  hipLaunchKernelGGL(cnn_k, dim3(512), dim3(1024), 0, stream,
                     vid, c1w, c1b, w2t, c2b, feats_sum);
  hipLaunchKernelGGL(base_k, dim3(128), dim3(256), 0, stream,
                     feats_sum, ev, fc_w, fc_b, base);
  hipLaunchKernelGGL(serial_k, dim3(NWG_S), dim3(256), 0, stream,
                     fca_w, fca_b, fc_w, action, base, pe, seq, out);
}